// Round 12
// baseline (198.297 us; speedup 1.0000x reference)
//
#include <hip/hip_runtime.h>
#include <math.h>

// z:  (2,1,256,256,64)  idx = b*4194304 + x*16384 + y*64 + k
// tg: (2,3,256,256,64)  idx = b*12582912 + c*4194304 + x*16384 + y*64 + k
//
// FLOAT2 REMAP: wave = 2 cells (x,y0),(x,y0+1); half h = lane>>5 owns cell
// (x,y0+h); lane j = lane&31 holds k = {2j, 2j+1} as a float2.
//  - 18 dwordx2 loads per wave (2 cells) vs 36 dword (R10): coalesced 256B/half
//  - k+1 for even k is IN-REGISTER (.y); odd k needs 1 shfl/row (not per-k)
//  - math is identical even/odd scalar pairs (v_pk-packable), R10 operand order
//  - width-64 shfls (proven codegen): all cross-lane/half leaks (j=31 comp1,
//    j=0 dzm0, lane31<->32) land only in k=63 / k=0 masked slots
// Block = 4 waves = 4 x-columns x one y-pair. Grid = 2*64*128 = 16384.
//
// ws layout (floats), 32 slices x 258:
//   sl[p*258 + 0]=smooth, +1=div, +2+b*64+k = s1, +130+b*64+k = s2

__global__ __launch_bounds__(512) void zero_ws_kernel(float* ws) {
    for (int i = threadIdx.x; i < 32 * 258; i += 512) ws[i] = 0.0f;
}

__global__ __launch_bounds__(256, 4) void fused_loss_kernel(
    const float* __restrict__ zin, const float* __restrict__ tg,
    float* __restrict__ ws)
{
    __shared__ float r1[4][2][64];
    __shared__ float r2[4][2][64];
    __shared__ float rsc[4][2];

    const int tid  = threadIdx.x;
    const int lane = tid & 63;
    const int w    = tid >> 6;
    const int j    = lane & 31;
    const int h    = lane >> 5;

    // blockIdx = bb*8192 + Y*64 + X ; wave w -> x = 4X+w ; halves y = 2Y+h
    const int bb   = blockIdx.x >> 13;
    const int rest = blockIdx.x & 8191;
    const int X    = rest & 63;
    const int Y    = rest >> 6;
    const int x    = (X << 2) | w;
    const int y    = (Y << 1) | h;
    const int k0   = j << 1;               // even k; lane holds k0, k0+1

    const int xp = x < 255 ? x + 1 : 255;
    const int yp = y < 255 ? y + 1 : 255;
    const int xm = x > 0 ? x - 1 : 0;
    const int ym = y > 0 ? y - 1 : 0;

    const int o00 = x  * 16384 + y  * 64 + k0;
    const int o10 = xp * 16384 + y  * 64 + k0;
    const int o01 = x  * 16384 + yp * 64 + k0;
    const int o11 = xp * 16384 + yp * 64 + k0;

    // ---- all row loads up front (float2 each) ----
    const float* zb = zin + ((size_t)bb << 22);
    float2 zC  = *(const float2*)&zb[o00];
    float2 zE  = *(const float2*)&zb[o10];
    float2 zN  = *(const float2*)&zb[o01];
    float2 zNE = *(const float2*)&zb[o11];
    float2 zW  = *(const float2*)&zb[xm * 16384 + y * 64 + k0];
    float2 zS  = *(const float2*)&zb[x * 16384 + ym * 64 + k0];

    const float* tbx = tg + (((size_t)bb * 3) << 22);
    const float* tby = tbx + 4194304;
    const float* tbz = tbx + 8388608;
    float2 bx00 = *(const float2*)&tbx[o00], bx10 = *(const float2*)&tbx[o10];
    float2 bx01 = *(const float2*)&tbx[o01], bx11 = *(const float2*)&tbx[o11];
    float2 by00 = *(const float2*)&tby[o00], by10 = *(const float2*)&tby[o10];
    float2 by01 = *(const float2*)&tby[o01], by11 = *(const float2*)&tby[o11];
    float2 bz00 = *(const float2*)&tbz[o00], bz10 = *(const float2*)&tbz[o10];
    float2 bz01 = *(const float2*)&tbz[o01], bz11 = *(const float2*)&tbz[o11];

    // ---- next-lane even-k values (z[k0+2]) for odd-k neighbors ----
    float zCn  = __shfl_down(zC.x,  1, 64);  // leaks at j=31 land in masked k=63
    float zEn  = __shfl_down(zE.x,  1, 64);
    float zNn  = __shfl_down(zN.x,  1, 64);
    float zNEn = __shfl_down(zNE.x, 1, 64);
    float zWn  = __shfl_down(zW.x,  1, 64);
    float zSn  = __shfl_down(zS.x,  1, 64);

    // dz rows: comp0 = dz[k0] (in-register), comp1 = dz[k0+1] (uses shfl)
    float dzC0  = zC.y  - zC.x,  dzC1  = zCn  - zC.y;
    float dzE0  = zE.y  - zE.x,  dzE1  = zEn  - zE.y;
    float dzN0  = zN.y  - zN.x,  dzN1  = zNn  - zN.y;
    float dzNE0 = zNE.y - zNE.x, dzNE1 = zNEn - zNE.y;
    float dzW0  = zW.y  - zW.x,  dzW1  = zWn  - zW.y;
    float dzS0  = zS.y  - zS.x,  dzS1  = zSn  - zS.y;

    float dzm0 = __shfl_up(dzC1, 1, 64);    // dz[k0-1]; j=0 garbage (k=0 masked)
    float dzp1 = __shfl_down(dzC0, 1, 64);  // dz[k0+2]; j=31 garbage (masked)
    // dzm for k0+1 = dzC0 ; dzp for k0 = dzC1 (in-register)

    // std partials: k0 always <63; k0+1 valid unless j==31 (k=63)
    float s10 = dzC0,               s20 = dzC0 * dzC0;
    float s11 = (j < 31) ? dzC1 : 0.0f;
    float s21 = (j < 31) ? dzC1 * dzC1 : 0.0f;

    // ---- smooth: k in [1,61] -> comp0 j in [1,30], comp1 j in [0,30] ----
    float sm = 0.0f;
    if (x >= 1 && x <= 254) {
        bool yok = (y >= 1 && y <= 254);
        if (yok && j >= 1 && j <= 30) {
            float lap = 6.0f * dzC0 * dzC0
                      - dzW0 * dzW0 - dzE0 * dzE0
                      - dzS0 * dzS0 - dzN0 * dzN0
                      - dzm0 * dzm0 - dzC1 * dzC1;
            sm += lap * lap;
        }
        if (yok && j <= 30) {
            float lap = 6.0f * dzC1 * dzC1
                      - dzW1 * dzW1 - dzE1 * dzE1
                      - dzS1 * dzS1 - dzN1 * dzN1
                      - dzC0 * dzC0 - dzp1 * dzp1;
            sm += lap * lap;
        }
    }

    // ---- div: comp0 (even k<=62) all j; comp1 (odd k) j<31 ----
    float dv = 0.0f;
    if (x < 255) {
        float bxA0 = bx00.x + bx01.x, bxA1 = bx00.y + bx01.y;
        float bxB0 = bx10.x + bx11.x, bxB1 = bx10.y + bx11.y;
        float bxC0 = bxB0 + bx00.x,  bxC1 = bxB1 + bx00.y;
        float bxD0 = bxB0 + bx01.x,  bxD1 = bxB1 + bx01.y;
        float byQ0 = by00.x + by10.x, byQ1 = by00.y + by10.y;
        float byP0 = by01.x + by11.x, byP1 = by01.y + by11.y;
        float byR0 = byP0 + by10.x,  byR1 = byP1 + by10.y;
        float byS0 = byP0 + by00.x,  byS1 = byP1 + by00.y;
        float bzT0 = ((bz00.x + bz10.x) + bz01.x) + bz11.x;
        float bzT1 = ((bz00.y + bz10.y) + bz01.y) + bz11.y;

        float bxAs = __shfl_down(bxA0, 1, 64);  // b-sums at k0+2 (for odd k's k+1)
        float bxBs = __shfl_down(bxB0, 1, 64);
        float bxCs = __shfl_down(bxC0, 1, 64);
        float bxDs = __shfl_down(bxD0, 1, 64);
        float byQs = __shfl_down(byQ0, 1, 64);
        float byPs = __shfl_down(byP0, 1, 64);
        float byRs = __shfl_down(byR0, 1, 64);
        float bySs = __shfl_down(byS0, 1, 64);
        float bzTs = __shfl_down(bzT0, 1, 64);

        const float c6 = 1.0f / 6.0f;
        if (y < 255) {
            // comp0: k = k0 (b@k = comp0, b@k+1 = comp1 in-register)
            float adz00 = fabsf(dzC0), adz10 = fabsf(dzE0);
            float adz01 = fabsf(dzN0), adz11 = fabsf(dzNE0);
            float num =
                0.125f * ( (bxB0 + bxB1) * (adz10 + adz11)
                         - (bxA0 + bxA1) * (adz00 + adz01)
                         + (byP0 + byP1) * (adz01 + adz11)
                         - (byQ0 + byQ1) * (adz00 + adz10) )
              + 0.25f * ( bzT1 - bzT0 );
            num += c6 * ( bxC1 * (zC.y - zE.y)
                        + bxD1 * (zN.y - zNE.y)
                        + byR1 * (zE.y - zNE.y)
                        + byS1 * (zC.y - zN.y)
                        - bxC0 * (zC.x - zE.x)
                        - bxD0 * (zN.x - zNE.x)
                        - byR0 * (zE.x - zNE.x)
                        - byS0 * (zC.x - zN.x) );
            float sbx = (bxA0 + bxB0) + (bxA1 + bxB1);
            float sby = (byQ0 + byP0) + (byQ1 + byP1);
            float sbz = bzT0 + bzT1;
            float den = 0.015625f * (sbx * sbx + sby * sby + sbz * sbz) + 1e-10f;
            dv = num * num / den;

            if (j < 31) {
                // comp1: k = k0+1 (b@k = comp1, b@k+1 = shfl'd next-even sums)
                float a00 = fabsf(dzC1), a10 = fabsf(dzE1);
                float a01 = fabsf(dzN1), a11 = fabsf(dzNE1);
                float num1 =
                    0.125f * ( (bxB1 + bxBs) * (a10 + a11)
                             - (bxA1 + bxAs) * (a00 + a01)
                             + (byP1 + byPs) * (a01 + a11)
                             - (byQ1 + byQs) * (a00 + a10) )
                  + 0.25f * ( bzTs - bzT1 );
                num1 += c6 * ( bxCs * (zCn - zEn)
                             + bxDs * (zNn - zNEn)
                             + byRs * (zEn - zNEn)
                             + bySs * (zCn - zNn)
                             - bxC1 * (zC.y - zE.y)
                             - bxD1 * (zN.y - zNE.y)
                             - byR1 * (zE.y - zNE.y)
                             - byS1 * (zC.y - zN.y) );
                float sbx1 = (bxA1 + bxB1) + (bxAs + bxBs);
                float sby1 = (byQ1 + byP1) + (byQs + byPs);
                float sbz1 = bzT1 + bzTs;
                float den1 = 0.015625f * (sbx1 * sbx1 + sby1 * sby1 + sbz1 * sbz1) + 1e-10f;
                dv += num1 * num1 / den1;
            }
        }
    }

    // ---- reductions (sm/dv cover both cells of the wave) ----
    #pragma unroll
    for (int off = 32; off > 0; off >>= 1) {
        sm += __shfl_down(sm, off, 64);
        dv += __shfl_down(dv, off, 64);
    }
    { float2 v; v.x = s10; v.y = s11; *(float2*)&r1[w][h][k0] = v; }
    { float2 v; v.x = s20; v.y = s21; *(float2*)&r2[w][h][k0] = v; }
    if (lane == 0) { rsc[w][0] = sm; rsc[w][1] = dv; }
    __syncthreads();

    if (tid < 64) {
        float a   = ((r1[0][0][tid] + r1[0][1][tid]) + (r1[1][0][tid] + r1[1][1][tid]))
                  + ((r1[2][0][tid] + r1[2][1][tid]) + (r1[3][0][tid] + r1[3][1][tid]));
        float b2r = ((r2[0][0][tid] + r2[0][1][tid]) + (r2[1][0][tid] + r2[1][1][tid]))
                  + ((r2[2][0][tid] + r2[2][1][tid]) + (r2[3][0][tid] + r2[3][1][tid]));
        float* sl = ws + (blockIdx.x & 31) * 258;
        if (tid < 63) {
            atomicAdd(&sl[2 + bb * 64 + tid],   a);
            atomicAdd(&sl[130 + bb * 64 + tid], b2r);
        }
        if (tid == 0) atomicAdd(&sl[0], rsc[0][0] + rsc[1][0] + rsc[2][0] + rsc[3][0]);
        if (tid == 1) atomicAdd(&sl[1], rsc[0][1] + rsc[1][1] + rsc[2][1] + rsc[3][1]);
    }
}

__global__ __launch_bounds__(128) void finalize_kernel(const float* __restrict__ ws,
                                                       float* __restrict__ out)
{
    __shared__ double red[128];
    const int t = threadIdx.x;
    double stdv = 0.0;
    {
        int k = t & 63, bb = t >> 6;
        if (k < 63) {
            double s1 = 0.0, s2 = 0.0;
            for (int p = 0; p < 32; ++p) {
                s1 += (double)ws[p * 258 + 2 + bb * 64 + k];
                s2 += (double)ws[p * 258 + 130 + bb * 64 + k];
            }
            const double N = 65536.0;
            double var = (s2 - s1 * s1 / N) / (N - 1.0);
            stdv = sqrt(var > 0.0 ? var : 0.0);
        }
    }
    red[t] = stdv;
    __syncthreads();
    for (int off = 64; off > 0; off >>= 1) {
        if (t < off) red[t] += red[t + off];
        __syncthreads();
    }
    if (t == 0) {
        double smt = 0.0, dvt = 0.0;
        for (int p = 0; p < 32; ++p) {
            smt += (double)ws[p * 258 + 0];
            dvt += (double)ws[p * 258 + 1];
        }
        double loss_std    = red[0] / 126.0;
        double loss_smooth = smt / (2.0 * 254.0 * 254.0 * 61.0);
        double loss_div    = dvt / (2.0 * 255.0 * 255.0 * 63.0);
        out[0] = (float)(loss_div * 1e9);
        out[1] = (float)(loss_smooth * 10.0 + loss_std * 100.0);
    }
}

extern "C" void kernel_launch(void* const* d_in, const int* in_sizes, int n_in,
                              void* d_out, int out_size, void* d_ws, size_t ws_size,
                              hipStream_t stream) {
    const float* z  = (const float*)d_in[0];   // outputs (2,1,256,256,64)
    const float* tg = (const float*)d_in[1];   // targets (2,3,256,256,64)
    float* out = (float*)d_out;
    float* ws  = (float*)d_ws;

    zero_ws_kernel<<<1, 512, 0, stream>>>(ws);
    // 2 batches x (64 x-tiles x 128 y-pairs) = 16384 blocks, 4 waves each
    fused_loss_kernel<<<16384, 256, 0, stream>>>(z, tg, ws);
    finalize_kernel<<<1, 128, 0, stream>>>(ws, out);
}

// Round 13
// 184.410 us; speedup vs baseline: 1.0753x; 1.0753x over previous
//
#include <hip/hip_runtime.h>
#include <math.h>

// z:  (2,1,256,256,64)  idx = b*4194304 + x*16384 + y*64 + k
// tg: (2,3,256,256,64)  idx = b*12582912 + c*4194304 + x*16384 + y*64 + k
//
// wave = one (x,y) cell, lane = k (R10 structure: best measured, 64.5 us).
// R13 change: x,y forced to SGPRs via readfirstlane (they ARE wave-uniform,
// derived from tid>>6, but the compiler can't prove it). All 18 row loads
// then use scalar base + shared lane voffset -> address arithmetic moves
// from VALU (~50 inst/wave, 12% of issue) to the parallel SALU pipe; x/y
// guards become scalar branches. Values bit-identical; TLP unchanged.
// R9/R12 lesson kept: NO work-per-wave amplification (it trades occupancy
// 69->42% and loses).
// Block = 4 waves = 2x2 cells. Grid = 2 x 128x128 = 32768.
//
// ws layout (floats), 32 slices x 258:
//   sl[p*258 + 0]=smooth, +1=div, +2+b*64+k = s1, +130+b*64+k = s2

__global__ __launch_bounds__(512) void zero_ws_kernel(float* ws) {
    for (int i = threadIdx.x; i < 32 * 258; i += 512) ws[i] = 0.0f;
}

__global__ __launch_bounds__(256, 4) void fused_loss_kernel(
    const float* __restrict__ zin, const float* __restrict__ tg,
    float* __restrict__ ws)
{
    __shared__ float r1[4][64];
    __shared__ float r2[4][64];
    __shared__ float rsc[4][2];

    const int tid  = threadIdx.x;
    const int lane = tid & 63;
    const int w    = tid >> 6;

    // blockIdx = bb*16384 + ty*128 + tx ; wave w -> cell (2tx + (w>>1), 2ty + (w&1))
    const int bb   = blockIdx.x >> 14;
    const int rest = blockIdx.x & 16383;
    const int tx   = rest & 127;
    const int ty   = rest >> 7;
    // x,y are wave-uniform; readfirstlane pins them (and everything derived)
    // to SGPRs -> scalar addressing + scalar guards.
    const int x    = __builtin_amdgcn_readfirstlane((tx << 1) | (w >> 1));
    const int y    = __builtin_amdgcn_readfirstlane((ty << 1) | (w & 1));

    const int xp = x < 255 ? x + 1 : 255;
    const int yp = y < 255 ? y + 1 : 255;
    const int xm = x > 0 ? x - 1 : 0;
    const int ym = y > 0 ? y - 1 : 0;

    const int b00 = x  * 16384 + y  * 64;   // scalar row bases
    const int b10 = xp * 16384 + y  * 64;
    const int b01 = x  * 16384 + yp * 64;
    const int b11 = xp * 16384 + yp * 64;
    const int bW  = xm * 16384 + y  * 64;
    const int bS  = x  * 16384 + ym * 64;

    // ---- all row loads issued up front: scalar base + shared lane offset ----
    const float* zb = zin + ((size_t)bb << 22);
    float zC  = zb[b00 + lane];
    float zE  = zb[b10 + lane];
    float zN  = zb[b01 + lane];
    float zNE = zb[b11 + lane];
    float zW  = zb[bW  + lane];
    float zS  = zb[bS  + lane];

    const float* tbx = tg + (((size_t)bb * 3) << 22);
    const float* tby = tbx + 4194304;
    const float* tbz = tbx + 8388608;
    float bx00 = tbx[b00 + lane], bx10 = tbx[b10 + lane];
    float bx01 = tbx[b01 + lane], bx11 = tbx[b11 + lane];
    float by00 = tby[b00 + lane], by10 = tby[b10 + lane];
    float by01 = tby[b01 + lane], by11 = tby[b11 + lane];
    float bz00 = tbz[b00 + lane], bz10 = tbz[b10 + lane];
    float bz01 = tbz[b01 + lane], bz11 = tbz[b11 + lane];

    // ---- z k+1 neighbors + dz rows ----
    float zCp  = __shfl_down(zC,  1, 64);   // lane63 garbage (masked k<63)
    float zEp  = __shfl_down(zE,  1, 64);
    float zNp  = __shfl_down(zN,  1, 64);
    float zNEp = __shfl_down(zNE, 1, 64);
    float zWp  = __shfl_down(zW,  1, 64);
    float zSp  = __shfl_down(zS,  1, 64);

    float dz   = zCp  - zC;
    float dzE  = zEp  - zE;
    float dzN  = zNp  - zN;
    float dzNE = zNEp - zNE;
    float dzW  = zWp  - zW;
    float dzS  = zSp  - zS;

    float dzm = __shfl_up(dz, 1, 64);       // dz[k-1]; lane0 garbage (masked)
    float dzp = __shfl_down(dz, 1, 64);     // dz[k+1]

    // std partials (k<63 valid) -- covers ALL x,y
    float s1 = (lane < 63) ? dz : 0.0f;
    float s2 = (lane < 63) ? dz * dz : 0.0f;

    // ---- smooth (scalar xy guard + lane mask; loads/shfls already done) ----
    float sm = 0.0f;
    if (x >= 1 && x <= 254 && y >= 1 && y <= 254) {
        if (lane >= 1 && lane <= 61) {
            float lap = 6.0f * dz * dz
                      - dzW * dzW - dzE * dzE
                      - dzS * dzS - dzN * dzN
                      - dzm * dzm - dzp * dzp;
            sm = lap * lap;
        }
    }

    // ---- div (scalar xy guard; pre-summed b shfls: 9 instead of 12) ----
    float dv = 0.0f;
    if (x < 255 && y < 255) {
        float bxA = bx00 + bx01;            // W face pair
        float bxB = bx10 + bx11;            // E face pair
        float bxC = bxB + bx00;             // bx00+bx10+bx11
        float bxD = bxB + bx01;             // bx01+bx11+bx10
        float byQ = by00 + by10;            // S face pair
        float byP = by01 + by11;            // N face pair
        float byR = byP + by10;             // by10+by11+by01
        float byS = byP + by00;             // by00+by01+by11
        float bzT = ((bz00 + bz10) + bz01) + bz11;

        float bxAp = __shfl_down(bxA, 1, 64);
        float bxBp = __shfl_down(bxB, 1, 64);
        float bxCp = __shfl_down(bxC, 1, 64);
        float bxDp = __shfl_down(bxD, 1, 64);
        float byQp = __shfl_down(byQ, 1, 64);
        float byPp = __shfl_down(byP, 1, 64);
        float byRp = __shfl_down(byR, 1, 64);
        float bySp = __shfl_down(byS, 1, 64);
        float bzTp = __shfl_down(bzT, 1, 64);

        if (lane < 63) {
            float adz00 = fabsf(dz),  adz10 = fabsf(dzE);
            float adz01 = fabsf(dzN), adz11 = fabsf(dzNE);

            float num =
                0.125f * ( (bxB + bxBp) * (adz10 + adz11)
                         - (bxA + bxAp) * (adz00 + adz01)
                         + (byP + byPp) * (adz01 + adz11)
                         - (byQ + byQp) * (adz00 + adz10) )
              + 0.25f * ( bzTp - bzT );

            const float c6 = 1.0f / 6.0f;
            num += c6 * ( bxCp * (zCp - zEp)
                        + bxDp * (zNp - zNEp)
                        + byRp * (zEp - zNEp)
                        + bySp * (zCp - zNp)
                        - bxC * (zC - zE)
                        - bxD * (zN - zNE)
                        - byR * (zE - zNE)
                        - byS * (zC - zN) );

            float sbx = (bxA + bxB) + (bxAp + bxBp);
            float sby = (byQ + byP) + (byQp + byPp);
            float sbz = bzT + bzTp;
            float den = 0.015625f * (sbx * sbx + sby * sby + sbz * sbz) + 1e-10f;
            dv = num * num / den;
        }
    }

    // ---- reductions ----
    #pragma unroll
    for (int off = 32; off > 0; off >>= 1) {
        sm += __shfl_down(sm, off, 64);
        dv += __shfl_down(dv, off, 64);
    }
    r1[w][lane] = s1;
    r2[w][lane] = s2;
    if (lane == 0) { rsc[w][0] = sm; rsc[w][1] = dv; }
    __syncthreads();

    if (tid < 64) {
        float a   = r1[0][tid] + r1[1][tid] + r1[2][tid] + r1[3][tid];
        float b2r = r2[0][tid] + r2[1][tid] + r2[2][tid] + r2[3][tid];
        float* sl = ws + (blockIdx.x & 31) * 258;
        if (tid < 63) {
            atomicAdd(&sl[2 + bb * 64 + tid],   a);
            atomicAdd(&sl[130 + bb * 64 + tid], b2r);
        }
        if (tid == 0) atomicAdd(&sl[0], rsc[0][0] + rsc[1][0] + rsc[2][0] + rsc[3][0]);
        if (tid == 1) atomicAdd(&sl[1], rsc[0][1] + rsc[1][1] + rsc[2][1] + rsc[3][1]);
    }
}

__global__ __launch_bounds__(128) void finalize_kernel(const float* __restrict__ ws,
                                                       float* __restrict__ out)
{
    __shared__ double red[128];
    const int t = threadIdx.x;
    double stdv = 0.0;
    {
        int k = t & 63, bb = t >> 6;
        if (k < 63) {
            double s1 = 0.0, s2 = 0.0;
            for (int p = 0; p < 32; ++p) {
                s1 += (double)ws[p * 258 + 2 + bb * 64 + k];
                s2 += (double)ws[p * 258 + 130 + bb * 64 + k];
            }
            const double N = 65536.0;
            double var = (s2 - s1 * s1 / N) / (N - 1.0);
            stdv = sqrt(var > 0.0 ? var : 0.0);
        }
    }
    red[t] = stdv;
    __syncthreads();
    for (int off = 64; off > 0; off >>= 1) {
        if (t < off) red[t] += red[t + off];
        __syncthreads();
    }
    if (t == 0) {
        double smt = 0.0, dvt = 0.0;
        for (int p = 0; p < 32; ++p) {
            smt += (double)ws[p * 258 + 0];
            dvt += (double)ws[p * 258 + 1];
        }
        double loss_std    = red[0] / 126.0;
        double loss_smooth = smt / (2.0 * 254.0 * 254.0 * 61.0);
        double loss_div    = dvt / (2.0 * 255.0 * 255.0 * 63.0);
        out[0] = (float)(loss_div * 1e9);
        out[1] = (float)(loss_smooth * 10.0 + loss_std * 100.0);
    }
}

extern "C" void kernel_launch(void* const* d_in, const int* in_sizes, int n_in,
                              void* d_out, int out_size, void* d_ws, size_t ws_size,
                              hipStream_t stream) {
    const float* z  = (const float*)d_in[0];   // outputs (2,1,256,256,64)
    const float* tg = (const float*)d_in[1];   // targets (2,3,256,256,64)
    float* out = (float*)d_out;
    float* ws  = (float*)d_ws;

    zero_ws_kernel<<<1, 512, 0, stream>>>(ws);
    // 2 batches x 128x128 tiles of 2x2 cells = 32768 blocks
    fused_loss_kernel<<<32768, 256, 0, stream>>>(z, tg, ws);
    finalize_kernel<<<1, 128, 0, stream>>>(ws, out);
}